// Round 1
// baseline (595.958 us; speedup 1.0000x reference)
//
#include <hip/hip_runtime.h>

// Problem constants
#define NB 128
#define NL 1024
#define NE 512
#define NA 512
#define ND 512

typedef __attribute__((ext_vector_type(8))) short short8;
typedef __attribute__((ext_vector_type(4))) float f32x4;

static __device__ __forceinline__ unsigned short f2bf(float f) {
  unsigned int u = __float_as_uint(f);
  u += 0x7FFF + ((u >> 16) & 1);   // round-to-nearest-even
  return (unsigned short)(u >> 16);
}

// ---------------------------------------------------------------------------
// Kernel 1: pack W_enc [E][A] fp32 -> bf16 in MFMA B-fragment order.
// Bpack layout: [nf=0..31][ki=0..15][lane=0..63][j=0..7]
//   lane l needs B[k][n] with k = ki*32 + (l>>4)*8 + j, n = nf*16 + (l&15)
__global__ void k_pack_w(const float* __restrict__ W_enc,
                         unsigned short* __restrict__ Bpack) {
  int t = blockIdx.x * blockDim.x + threadIdx.x;  // 0..32767
  int lane = t & 63;
  int rest = t >> 6;       // 0..511
  int ki = rest & 15;
  int nf = rest >> 4;      // 0..31
  int col = nf * 16 + (lane & 15);
  int kbase = ki * 32 + (lane >> 4) * 8;
  short8 v;
#pragma unroll
  for (int j = 0; j < 8; ++j)
    v[j] = (short)f2bf(W_enc[(kbase + j) * NA + col]);
  *reinterpret_cast<short8*>(Bpack + (long)t * 8) = v;
}

// ---------------------------------------------------------------------------
// Kernel 2: att2[b][a] = dec[b,:] @ W_dec[:,a] + b_dec[a] + b_enc[a]
__global__ void k_att2(const float* __restrict__ dec,
                       const float* __restrict__ Wdec,
                       const float* __restrict__ b_enc,
                       const float* __restrict__ b_dec,
                       float* __restrict__ att2) {
  int b = blockIdx.x;
  int a = threadIdx.x;  // 512 threads
  float acc = b_enc[a] + b_dec[a];
  const float* drow = dec + b * ND;
#pragma unroll 4
  for (int d = 0; d < ND; ++d)
    acc += drow[d] * Wdec[d * NA + a];
  att2[b * NA + a] = acc;
}

// ---------------------------------------------------------------------------
// Kernel 3: fused scores GEMM.
// Block = 256 thr (4 waves), BM=64 rows of enc (as [B*L, E]).
// A tile staged in LDS as bf16 with XOR swizzle; B frags from Bpack (coalesced).
// Epilogue: relu(acc + att2[b][col]) * W_full[col], reduced over all 512 cols
// -> att[m] scalar per row. (b_full dropped: softmax-invariant.)
__global__ __launch_bounds__(256, 2) void k_scores(
    const float* __restrict__ enc, const unsigned short* __restrict__ Bpack,
    const float* __restrict__ att2, const float* __restrict__ wfull,
    float* __restrict__ att) {
  extern __shared__ char smem[];
  float* a2row = (float*)(smem + 65536);          // 512 f
  float* wf    = (float*)(smem + 65536 + 2048);   // 512 f

  const int t = threadIdx.x;
  const int blk = blockIdx.x;
  const long row0 = (long)blk * 64;
  const int b = blk >> 4;   // 64*16 = 1024 rows per batch

  // ---- stage A: 64 rows x 512 cols fp32 -> bf16, swizzled ----
  {
    const float* src = enc + row0 * NE;
#pragma unroll
    for (int i = 0; i < 16; ++i) {
      int c = i * 256 + t;          // chunk id 0..4095, 8 floats each
      int row = c >> 6;
      int colb = (c & 63) * 16;     // byte offset within row (8 bf16 = 16B)
      const float4* p = reinterpret_cast<const float4*>(src + (long)c * 8);
      float4 x0 = p[0];
      float4 x1 = p[1];
      short8 o;
      o[0] = (short)f2bf(x0.x); o[1] = (short)f2bf(x0.y);
      o[2] = (short)f2bf(x0.z); o[3] = (short)f2bf(x0.w);
      o[4] = (short)f2bf(x1.x); o[5] = (short)f2bf(x1.y);
      o[6] = (short)f2bf(x1.z); o[7] = (short)f2bf(x1.w);
      int byte = (row * 1024 + colb) ^ ((row & 7) << 4);
      *reinterpret_cast<short8*>(smem + byte) = o;
    }
    a2row[t]       = att2[b * NA + t];
    a2row[t + 256] = att2[b * NA + t + 256];
    wf[t]          = wfull[t];
    wf[t + 256]    = wfull[t + 256];
  }
  __syncthreads();

  const int lane = t & 63;
  const int wave = t >> 6;
  const int l15 = lane & 15;
  const int lq = lane >> 4;
  const int arow = wave * 16 + l15;
  const int abase = arow * 1024;
  const int aswz = (arow & 7) << 4;

  float partial[4] = {0.f, 0.f, 0.f, 0.f};
  const short8* bp = reinterpret_cast<const short8*>(Bpack);

  for (int nc = 0; nc < 4; ++nc) {
    f32x4 acc[8];
#pragma unroll
    for (int cf = 0; cf < 8; ++cf) acc[cf] = (f32x4){0.f, 0.f, 0.f, 0.f};
#pragma unroll
    for (int ki = 0; ki < 16; ++ki) {
      int abyte = (abase + ki * 64 + lq * 16) ^ aswz;
      short8 av = *reinterpret_cast<const short8*>(smem + abyte);
#pragma unroll
      for (int cf = 0; cf < 8; ++cf) {
        int nf = nc * 8 + cf;
        short8 bv = bp[(nf * 16 + ki) * 64 + lane];
        acc[cf] = __builtin_amdgcn_mfma_f32_16x16x32_bf16(av, bv, acc[cf], 0, 0, 0);
      }
    }
#pragma unroll
    for (int cf = 0; cf < 8; ++cf) {
      int col = nc * 128 + cf * 16 + l15;
      float a2 = a2row[col];
      float w = wf[col];
#pragma unroll
      for (int r = 0; r < 4; ++r) {
        float v = acc[cf][r] + a2;
        partial[r] += fmaxf(v, 0.f) * w;
      }
    }
  }
  // reduce over the 16 cols held across lanes (bits 0..3 of lane)
#pragma unroll
  for (int r = 0; r < 4; ++r) {
    float p = partial[r];
    p += __shfl_xor(p, 1);
    p += __shfl_xor(p, 2);
    p += __shfl_xor(p, 4);
    p += __shfl_xor(p, 8);
    partial[r] = p;
  }
  if (l15 == 0) {
    long m = row0 + wave * 16 + lq * 4;
#pragma unroll
    for (int r = 0; r < 4; ++r) att[m + r] = partial[r];
  }
}

// ---------------------------------------------------------------------------
// Kernel 4: softmax over L=1024 per batch row. alpha written to d_out.
__global__ void k_softmax(const float* __restrict__ att,
                          float* __restrict__ alpha) {
  int b = blockIdx.x;
  int t = threadIdx.x;  // 256
  const float* row = att + b * NL;
  float v0 = row[t], v1 = row[t + 256], v2 = row[t + 512], v3 = row[t + 768];
  float m = fmaxf(fmaxf(v0, v1), fmaxf(v2, v3));
#pragma unroll
  for (int off = 1; off < 64; off <<= 1) m = fmaxf(m, __shfl_xor(m, off));
  __shared__ float rm[4];
  int lane = t & 63, w = t >> 6;
  if (lane == 0) rm[w] = m;
  __syncthreads();
  m = fmaxf(fmaxf(rm[0], rm[1]), fmaxf(rm[2], rm[3]));
  float e0 = expf(v0 - m), e1 = expf(v1 - m), e2 = expf(v2 - m), e3 = expf(v3 - m);
  float s = e0 + e1 + e2 + e3;
#pragma unroll
  for (int off = 1; off < 64; off <<= 1) s += __shfl_xor(s, off);
  __shared__ float rs[4];
  if (lane == 0) rs[w] = s;
  __syncthreads();
  s = rs[0] + rs[1] + rs[2] + rs[3];
  float inv = 1.f / s;
  float* arow = alpha + b * NL;
  arow[t] = e0 * inv;
  arow[t + 256] = e1 * inv;
  arow[t + 512] = e2 * inv;
  arow[t + 768] = e3 * inv;
}

// ---------------------------------------------------------------------------
// Kernel 5: partial weighted sum. Grid = 128 b * 8 l-chunks.
// Each block: 256 threads, thread owns 2 e-cols (float2), 128 l-iterations.
__global__ void k_wpart(const float* __restrict__ enc,
                        const float* __restrict__ alpha,
                        float* __restrict__ part) {
  int bid = blockIdx.x;
  int b = bid >> 3, lc = bid & 7;
  int t = threadIdx.x;
  const float* base = enc + (long)(b * NL + lc * 128) * NE;
  const float* al = alpha + b * NL + lc * 128;
  float ax = 0.f, ay = 0.f;
#pragma unroll 4
  for (int l = 0; l < 128; ++l) {
    float a = al[l];
    const float2 x = *reinterpret_cast<const float2*>(base + (long)l * NE + t * 2);
    ax += a * x.x;
    ay += a * x.y;
  }
  float* dst = part + (long)bid * NE + t * 2;
  dst[0] = ax;
  dst[1] = ay;
}

// ---------------------------------------------------------------------------
// Kernel 6: reduce 8 l-chunk partials -> weighted [B,E] into d_out.
__global__ void k_wreduce(const float* __restrict__ part,
                          float* __restrict__ outw) {
  int g = blockIdx.x * 256 + threadIdx.x;  // 0..65535
  int b = g >> 9, e = g & 511;
  float s = 0.f;
#pragma unroll
  for (int lc = 0; lc < 8; ++lc) s += part[(long)(b * 8 + lc) * NE + e];
  outw[g] = s;
}

// ---------------------------------------------------------------------------
extern "C" void kernel_launch(void* const* d_in, const int* in_sizes, int n_in,
                              void* d_out, int out_size, void* d_ws, size_t ws_size,
                              hipStream_t stream) {
  const float* enc    = (const float*)d_in[0];  // [B,L,E]
  const float* dec    = (const float*)d_in[1];  // [B,D]
  const float* W_enc  = (const float*)d_in[2];  // [E,A]
  const float* b_enc  = (const float*)d_in[3];  // [A]
  const float* W_dec  = (const float*)d_in[4];  // [D,A]
  const float* b_dec  = (const float*)d_in[5];  // [A]
  const float* W_full = (const float*)d_in[6];  // [A]
  // d_in[7] = b_full: cancels in softmax, unused.

  float* out = (float*)d_out;
  float* weighted = out;                 // [B,E] = 65536
  float* alpha = out + NB * NE;          // [B,L] = 131072

  char* ws = (char*)d_ws;
  float* att2          = (float*)ws;                                   // 256 KB
  unsigned short* Bpk  = (unsigned short*)(ws + (256 << 10));          // 512 KB
  float* att           = (float*)(ws + (768 << 10));                   // 512 KB
  float* part          = (float*)(ws + (1280 << 10));                  // 2 MB

  hipLaunchKernelGGL(k_pack_w, dim3(128), dim3(256), 0, stream, W_enc, Bpk);
  hipLaunchKernelGGL(k_att2, dim3(NB), dim3(512), 0, stream, dec, W_dec, b_enc, b_dec, att2);
  hipLaunchKernelGGL(k_scores, dim3((NB * NL) / 64), dim3(256), 69632, stream,
                     enc, Bpk, att2, W_full, att);
  hipLaunchKernelGGL(k_softmax, dim3(NB), dim3(256), 0, stream, att, alpha);
  hipLaunchKernelGGL(k_wpart, dim3(NB * 8), dim3(256), 0, stream, enc, alpha, part);
  hipLaunchKernelGGL(k_wreduce, dim3(NB * NE / 256), dim3(256), 0, stream, part, weighted);
}

// Round 2
// 205.108 us; speedup vs baseline: 2.9056x; 2.9056x over previous
//
#include <hip/hip_runtime.h>

// Problem constants
#define NB 128
#define NL 1024
#define NE 512
#define NA 512
#define ND 512

typedef __attribute__((ext_vector_type(8))) short short8;
typedef __attribute__((ext_vector_type(4))) float f32x4;

static __device__ __forceinline__ unsigned short f2bf(float f) {
  unsigned int u = __float_as_uint(f);
  u += 0x7FFF + ((u >> 16) & 1);   // round-to-nearest-even
  return (unsigned short)(u >> 16);
}

// ---------------------------------------------------------------------------
// Kernel 1: pack W_enc [E][A] fp32 -> bf16 in MFMA B-fragment order.
// Bpack layout: [nf=0..31][ki=0..15][lane=0..63][j=0..7]
//   lane l needs B[k][n] with k = ki*32 + (l>>4)*8 + j, n = nf*16 + (l&15)
__global__ void k_pack_w(const float* __restrict__ W_enc,
                         unsigned short* __restrict__ Bpack) {
  int t = blockIdx.x * blockDim.x + threadIdx.x;  // 0..32767
  int lane = t & 63;
  int rest = t >> 6;       // 0..511
  int ki = rest & 15;
  int nf = rest >> 4;      // 0..31
  int col = nf * 16 + (lane & 15);
  int kbase = ki * 32 + (lane >> 4) * 8;
  short8 v;
#pragma unroll
  for (int j = 0; j < 8; ++j)
    v[j] = (short)f2bf(W_enc[(kbase + j) * NA + col]);
  *reinterpret_cast<short8*>(Bpack + (long)t * 8) = v;
}

// ---------------------------------------------------------------------------
// Kernel 2: att2[b][a] = dec[b,:] @ W_dec[:,a] + b_dec[a] + b_enc[a]
__global__ void k_att2(const float* __restrict__ dec,
                       const float* __restrict__ Wdec,
                       const float* __restrict__ b_enc,
                       const float* __restrict__ b_dec,
                       float* __restrict__ att2) {
  int b = blockIdx.x;
  int a = threadIdx.x;  // 512 threads
  float acc = b_enc[a] + b_dec[a];
  const float* drow = dec + b * ND;
#pragma unroll 4
  for (int d = 0; d < ND; ++d)
    acc += drow[d] * Wdec[d * NA + a];
  att2[b * NA + a] = acc;
}

// ---------------------------------------------------------------------------
// Kernel 3: fused scores GEMM, column-split across waves.
// Block = 256 thr (4 waves), BM=64 rows of enc (as [B*L, E]).
// Wave w computes ALL 64 rows x cols [w*128, w*128+128).
// A tile staged in LDS as bf16 with XOR swizzle; per-wave B frags from Bpack
// (coalesced, L2-resident) with double-buffered register prefetch.
// Epilogue: relu(acc + att2[b][col]) * W_full[col] reduced over cols
// (shfl within wave, LDS across waves) -> att[m]. (b_full softmax-invariant.)
__global__ __launch_bounds__(256, 2) void k_scores(
    const float* __restrict__ enc, const unsigned short* __restrict__ Bpack,
    const float* __restrict__ att2, const float* __restrict__ wfull,
    float* __restrict__ att) {
  extern __shared__ char smem[];
  float* a2row = (float*)(smem + 65536);          // 512 f
  float* wf    = (float*)(smem + 67584);          // 512 f
  float* red   = (float*)(smem + 69632);          // 4 waves x 64 rows

  const int t = threadIdx.x;
  const int blk = blockIdx.x;
  const long row0 = (long)blk * 64;
  const int b = blk >> 4;   // 64*16 = 1024 rows per batch

  // ---- stage A: 64 rows x 512 cols fp32 -> bf16, swizzled ----
  {
    const float* src = enc + row0 * NE;
#pragma unroll
    for (int i = 0; i < 16; ++i) {
      int c = i * 256 + t;          // chunk id 0..4095, 8 floats each
      int row = c >> 6;
      int colb = (c & 63) * 16;     // byte offset within row (8 bf16 = 16B)
      const float4* p = reinterpret_cast<const float4*>(src + (long)c * 8);
      float4 x0 = p[0];
      float4 x1 = p[1];
      short8 o;
      o[0] = (short)f2bf(x0.x); o[1] = (short)f2bf(x0.y);
      o[2] = (short)f2bf(x0.z); o[3] = (short)f2bf(x0.w);
      o[4] = (short)f2bf(x1.x); o[5] = (short)f2bf(x1.y);
      o[6] = (short)f2bf(x1.z); o[7] = (short)f2bf(x1.w);
      int byte = (row * 1024 + colb) ^ ((row & 7) << 4);
      *reinterpret_cast<short8*>(smem + byte) = o;
    }
    a2row[t]       = att2[b * NA + t];
    a2row[t + 256] = att2[b * NA + t + 256];
    wf[t]          = wfull[t];
    wf[t + 256]    = wfull[t + 256];
  }
  __syncthreads();

  const int lane = t & 63;
  const int wave = t >> 6;
  const int l15 = lane & 15;
  const int lq = lane >> 4;

  // Wave w's column chunk: nf = wave*8 + cf. Frag (cf,ki) at (cf*16+ki)*64+lane.
  const short8* bp_w = reinterpret_cast<const short8*>(Bpack)
                       + (size_t)wave * 8 * 16 * 64;

  f32x4 acc[4][8];
#pragma unroll
  for (int rt = 0; rt < 4; ++rt)
#pragma unroll
    for (int cf = 0; cf < 8; ++cf) acc[rt][cf] = (f32x4){0.f, 0.f, 0.f, 0.f};

  short8 bv[2][8];
#pragma unroll
  for (int cf = 0; cf < 8; ++cf) bv[0][cf] = bp_w[(cf * 16) * 64 + lane];

#pragma unroll
  for (int ki = 0; ki < 16; ++ki) {
    const int cur = ki & 1;
    const int nxt = cur ^ 1;
    if (ki < 15) {
#pragma unroll
      for (int cf = 0; cf < 8; ++cf)
        bv[nxt][cf] = bp_w[(cf * 16 + ki + 1) * 64 + lane];
    }
#pragma unroll
    for (int rt = 0; rt < 4; ++rt) {
      const int ar = rt * 16 + l15;
      const int abyte = (ar * 1024 + ki * 64 + lq * 16) ^ ((ar & 7) << 4);
      short8 av = *reinterpret_cast<const short8*>(smem + abyte);
#pragma unroll
      for (int cf = 0; cf < 8; ++cf)
        acc[rt][cf] =
            __builtin_amdgcn_mfma_f32_16x16x32_bf16(av, bv[cur][cf], acc[rt][cf], 0, 0, 0);
    }
  }

  // Epilogue: relu + project + reduce over this wave's 128 cols.
  // C layout: row = rt*16 + lq*4 + r, col = wave*128 + cf*16 + l15.
  float partial[4][4];
#pragma unroll
  for (int rt = 0; rt < 4; ++rt)
#pragma unroll
    for (int r = 0; r < 4; ++r) partial[rt][r] = 0.f;

#pragma unroll
  for (int cf = 0; cf < 8; ++cf) {
    int col = wave * 128 + cf * 16 + l15;
    float a2 = a2row[col];
    float w = wf[col];
#pragma unroll
    for (int rt = 0; rt < 4; ++rt)
#pragma unroll
      for (int r = 0; r < 4; ++r) {
        float v = acc[rt][cf][r] + a2;
        partial[rt][r] += fmaxf(v, 0.f) * w;
      }
  }
  // reduce across the 16 l15 lanes
#pragma unroll
  for (int rt = 0; rt < 4; ++rt)
#pragma unroll
    for (int r = 0; r < 4; ++r) {
      float p = partial[rt][r];
      p += __shfl_xor(p, 1);
      p += __shfl_xor(p, 2);
      p += __shfl_xor(p, 4);
      p += __shfl_xor(p, 8);
      partial[rt][r] = p;
    }
  if (l15 == 0) {
#pragma unroll
    for (int rt = 0; rt < 4; ++rt)
#pragma unroll
      for (int r = 0; r < 4; ++r)
        red[wave * 64 + rt * 16 + lq * 4 + r] = partial[rt][r];
  }
  __syncthreads();
  if (t < 64) att[row0 + t] = red[t] + red[64 + t] + red[128 + t] + red[192 + t];
}

// ---------------------------------------------------------------------------
// Kernel 4: softmax over L=1024 per batch row. alpha written to d_out.
__global__ void k_softmax(const float* __restrict__ att,
                          float* __restrict__ alpha) {
  int b = blockIdx.x;
  int t = threadIdx.x;  // 256
  const float* row = att + b * NL;
  float v0 = row[t], v1 = row[t + 256], v2 = row[t + 512], v3 = row[t + 768];
  float m = fmaxf(fmaxf(v0, v1), fmaxf(v2, v3));
#pragma unroll
  for (int off = 1; off < 64; off <<= 1) m = fmaxf(m, __shfl_xor(m, off));
  __shared__ float rm[4];
  int lane = t & 63, w = t >> 6;
  if (lane == 0) rm[w] = m;
  __syncthreads();
  m = fmaxf(fmaxf(rm[0], rm[1]), fmaxf(rm[2], rm[3]));
  float e0 = expf(v0 - m), e1 = expf(v1 - m), e2 = expf(v2 - m), e3 = expf(v3 - m);
  float s = e0 + e1 + e2 + e3;
#pragma unroll
  for (int off = 1; off < 64; off <<= 1) s += __shfl_xor(s, off);
  __shared__ float rs[4];
  if (lane == 0) rs[w] = s;
  __syncthreads();
  s = rs[0] + rs[1] + rs[2] + rs[3];
  float inv = 1.f / s;
  float* arow = alpha + b * NL;
  arow[t] = e0 * inv;
  arow[t + 256] = e1 * inv;
  arow[t + 512] = e2 * inv;
  arow[t + 768] = e3 * inv;
}

// ---------------------------------------------------------------------------
// Kernel 5: partial weighted sum. Grid = 128 b * 16 l-chunks, 128 threads.
// Thread owns 4 e-cols (float4), 64 l-iterations per chunk.
__global__ void k_wpart(const float* __restrict__ enc,
                        const float* __restrict__ alpha,
                        float* __restrict__ part) {
  int bid = blockIdx.x;          // 0..2047
  int b = bid >> 4, lc = bid & 15;
  int t = threadIdx.x;           // 0..127
  const float* base = enc + ((long)b * NL + lc * 64) * NE;
  const float* al = alpha + b * NL + lc * 64;
  float4 s = {0.f, 0.f, 0.f, 0.f};
#pragma unroll 4
  for (int l = 0; l < 64; ++l) {
    float a = al[l];
    const float4 x = *reinterpret_cast<const float4*>(base + (long)l * NE + t * 4);
    s.x += a * x.x;
    s.y += a * x.y;
    s.z += a * x.z;
    s.w += a * x.w;
  }
  *reinterpret_cast<float4*>(part + (long)bid * NE + t * 4) = s;
}

// ---------------------------------------------------------------------------
// Kernel 6: reduce 16 l-chunk partials -> weighted [B,E] into d_out.
__global__ void k_wreduce(const float* __restrict__ part,
                          float* __restrict__ outw) {
  int g = blockIdx.x * 256 + threadIdx.x;  // 0..65535
  int b = g >> 9, e = g & 511;
  float s = 0.f;
#pragma unroll
  for (int lc = 0; lc < 16; ++lc) s += part[(long)(b * 16 + lc) * NE + e];
  outw[g] = s;
}

// ---------------------------------------------------------------------------
extern "C" void kernel_launch(void* const* d_in, const int* in_sizes, int n_in,
                              void* d_out, int out_size, void* d_ws, size_t ws_size,
                              hipStream_t stream) {
  const float* enc    = (const float*)d_in[0];  // [B,L,E]
  const float* dec    = (const float*)d_in[1];  // [B,D]
  const float* W_enc  = (const float*)d_in[2];  // [E,A]
  const float* b_enc  = (const float*)d_in[3];  // [A]
  const float* W_dec  = (const float*)d_in[4];  // [D,A]
  const float* b_dec  = (const float*)d_in[5];  // [A]
  const float* W_full = (const float*)d_in[6];  // [A]
  // d_in[7] = b_full: cancels in softmax, unused.

  float* out = (float*)d_out;
  float* weighted = out;                 // [B,E] = 65536
  float* alpha = out + NB * NE;          // [B,L] = 131072

  char* ws = (char*)d_ws;
  float* att2          = (float*)ws;                                   // 256 KB
  unsigned short* Bpk  = (unsigned short*)(ws + (256 << 10));          // 512 KB
  float* att           = (float*)(ws + (768 << 10));                   // 512 KB
  float* part          = (float*)(ws + (1280 << 10));                  // 4 MB

  hipLaunchKernelGGL(k_pack_w, dim3(128), dim3(256), 0, stream, W_enc, Bpk);
  hipLaunchKernelGGL(k_att2, dim3(NB), dim3(512), 0, stream, dec, W_dec, b_enc, b_dec, att2);
  hipLaunchKernelGGL(k_scores, dim3((NB * NL) / 64), dim3(256), 70656, stream,
                     enc, Bpk, att2, W_full, att);
  hipLaunchKernelGGL(k_softmax, dim3(NB), dim3(256), 0, stream, att, alpha);
  hipLaunchKernelGGL(k_wpart, dim3(NB * 16), dim3(128), 0, stream, enc, alpha, part);
  hipLaunchKernelGGL(k_wreduce, dim3(NB * NE / 256), dim3(256), 0, stream, part, weighted);
}